// Round 5
// baseline (300.929 us; speedup 1.0000x reference)
//
#include <hip/hip_runtime.h>
#include <math.h>

#define NUM_GRAPHS 512
#define D 128
#define NEG 0.01f

typedef __attribute__((ext_vector_type(8)))  short    bf16x8;   // MFMA A/B frag (4 VGPR)
typedef __attribute__((ext_vector_type(16))) float    f32x16;   // MFMA C/D frag (32x32)
typedef __attribute__((ext_vector_type(2)))  int      i32x2;
typedef __attribute__((ext_vector_type(4)))  int      i32x4;

__device__ __forceinline__ unsigned short f2bf(float f) {
    unsigned u = __float_as_uint(f);
    u += 0x7fffu + ((u >> 16) & 1u);   // RNE
    return (unsigned short)(u >> 16);
}

__device__ __forceinline__ uint2 pack4(float4 v) {
    uint2 pk;
    pk.x = (unsigned)f2bf(v.x) | ((unsigned)f2bf(v.y) << 16);
    pk.y = (unsigned)f2bf(v.z) | ((unsigned)f2bf(v.w) << 16);
    return pk;
}

// exchange: a.rows32-63 <-> b.rows0-31  =>  a'={a.lo,b.lo}, b'={a.hi,b.hi}
#if __has_builtin(__builtin_amdgcn_permlane32_swap)
#define PLSWAP(a, b) do {                                                     \
    i32x2 _r = __builtin_amdgcn_permlane32_swap((int)(a), (int)(b), false, false); \
    (a) = (unsigned)_r[0]; (b) = (unsigned)_r[1];                             \
} while (0)
#else
#define PLSWAP(a, b) asm volatile("v_permlane32_swap_b32 %0, %1" : "+v"(a), "+v"(b))
#endif

// ---------------------------------------------------------------------------
// Kernel 1: per-graph segment max+mean AND plain node-major bf16 copy of X.
// grid=(NUM_GRAPHS,2) [y:0=topo,1=geom], block=256.
// xt[node][k]: k 0..127 = topo, 128..255 = geom (bf16, contiguous per node).
// ---------------------------------------------------------------------------
__global__ __launch_bounds__(256) void pool_kernel(
    const float* __restrict__ h_topo, const float* __restrict__ h_geom,
    const int* __restrict__ batch, int N, float* __restrict__ pooled,
    unsigned short* __restrict__ xt)
{
    const int g = blockIdx.x, t = blockIdx.y;
    const float* __restrict__ h = t ? h_geom : h_topo;
    const int koff = t ? 128 : 0;

    int lo = 0, hi = N;
    while (lo < hi) { int m = (lo + hi) >> 1; if (batch[m] < g) lo = m + 1; else hi = m; }
    const int start = lo; hi = N;
    while (lo < hi) { int m = (lo + hi) >> 1; if (batch[m] < g + 1) lo = m + 1; else hi = m; }
    const int end = lo;

    const int c = threadIdx.x & 31;   // float4 column
    const int r = threadIdx.x >> 5;   // 0..7 row phase
    const int kk = koff + c * 4;

    float4 mx  = make_float4(-INFINITY, -INFINITY, -INFINITY, -INFINITY);
    float4 mx2 = mx;
    float4 sm  = make_float4(0.f, 0.f, 0.f, 0.f);
    float4 sm2 = sm;

    int row = start + r;
    for (; row + 8 < end; row += 16) {
        float4 v = *(const float4*)(h + (size_t)row * D + c * 4);
        float4 w = *(const float4*)(h + (size_t)(row + 8) * D + c * 4);
        mx.x  = fmaxf(mx.x,  v.x); mx.y  = fmaxf(mx.y,  v.y);
        mx.z  = fmaxf(mx.z,  v.z); mx.w  = fmaxf(mx.w,  v.w);
        sm.x += v.x; sm.y += v.y; sm.z += v.z; sm.w += v.w;
        mx2.x = fmaxf(mx2.x, w.x); mx2.y = fmaxf(mx2.y, w.y);
        mx2.z = fmaxf(mx2.z, w.z); mx2.w = fmaxf(mx2.w, w.w);
        sm2.x += w.x; sm2.y += w.y; sm2.z += w.z; sm2.w += w.w;
        *(uint2*)(xt + (size_t)row * 256 + kk)       = pack4(v);
        *(uint2*)(xt + (size_t)(row + 8) * 256 + kk) = pack4(w);
    }
    if (row < end) {
        float4 v = *(const float4*)(h + (size_t)row * D + c * 4);
        mx.x  = fmaxf(mx.x,  v.x); mx.y  = fmaxf(mx.y,  v.y);
        mx.z  = fmaxf(mx.z,  v.z); mx.w  = fmaxf(mx.w,  v.w);
        sm.x += v.x; sm.y += v.y; sm.z += v.z; sm.w += v.w;
        *(uint2*)(xt + (size_t)row * 256 + kk) = pack4(v);
    }
    mx.x = fmaxf(mx.x, mx2.x); mx.y = fmaxf(mx.y, mx2.y);
    mx.z = fmaxf(mx.z, mx2.z); mx.w = fmaxf(mx.w, mx2.w);
    sm.x += sm2.x; sm.y += sm2.y; sm.z += sm2.z; sm.w += sm2.w;

    __shared__ float4 smx[256], ssm[256];
    smx[threadIdx.x] = mx; ssm[threadIdx.x] = sm;
    __syncthreads();
    #pragma unroll
    for (int s = 4; s > 0; s >>= 1) {
        if (r < s) {
            float4 a = smx[threadIdx.x + s * 32];
            float4 b = ssm[threadIdx.x + s * 32];
            float4 m0 = smx[threadIdx.x];
            float4 s0 = ssm[threadIdx.x];
            m0.x = fmaxf(m0.x, a.x); m0.y = fmaxf(m0.y, a.y);
            m0.z = fmaxf(m0.z, a.z); m0.w = fmaxf(m0.w, a.w);
            s0.x += b.x; s0.y += b.y; s0.z += b.z; s0.w += b.w;
            smx[threadIdx.x] = m0; ssm[threadIdx.x] = s0;
        }
        __syncthreads();
    }
    if (r == 0) {
        float4 m0 = smx[threadIdx.x], s0 = ssm[threadIdx.x];
        const float inv = 1.0f / fmaxf((float)(end - start), 1.0f);
        float4 mean = make_float4(s0.x * inv, s0.y * inv, s0.z * inv, s0.w * inv);
        if (end <= start) { m0 = make_float4(0,0,0,0); mean = make_float4(0,0,0,0); }
        float* dst = pooled + (size_t)g * 512 + t * 256;
        *(float4*)(dst + c * 4)       = m0;
        *(float4*)(dst + 128 + c * 4) = mean;
    }
}

// ---------------------------------------------------------------------------
// Kernel 2: per-graph bias P[g][j] = b1[j] + pooled[g] . W1[pooled rows][j]
// ---------------------------------------------------------------------------
__global__ __launch_bounds__(256) void pmat_kernel(
    const float* __restrict__ pooled, const float* __restrict__ W1,
    const float* __restrict__ b1, float* __restrict__ P)
{
    const int g = blockIdx.x;
    const int j = threadIdx.x;

    __shared__ float pl[512];
    pl[j]       = pooled[(size_t)g * 512 + j];
    pl[j + 256] = pooled[(size_t)g * 512 + 256 + j];
    __syncthreads();

    float acc = b1[j];
    #pragma unroll 8
    for (int k = 0; k < 256; ++k)          // t_max,t_mean -> W1 rows 128..383
        acc += pl[k] * W1[(size_t)(128 + k) * 256 + j];
    #pragma unroll 8
    for (int k = 0; k < 256; ++k)          // g_max,g_mean -> W1 rows 512..767
        acc += pl[256 + k] * W1[(size_t)(512 + k) * 256 + j];

    P[(size_t)g * 256 + j] = acc;
}

// ---------------------------------------------------------------------------
// Kernel 3: weight pre-convert to transposed bf16.
// W1bT[c][k] = bf16(W1[kmap(k)][c]), kmap(k) = k<128 ? k : k+256
// W2bT[j][c] = bf16(W2[c][j])
// ---------------------------------------------------------------------------
__global__ __launch_bounds__(256) void wconv_kernel(
    const float* __restrict__ W1, const float* __restrict__ W2,
    unsigned short* __restrict__ W1bT, unsigned short* __restrict__ W2bT)
{
    const int idx = blockIdx.x * 256 + threadIdx.x;
    if (idx < 256 * 256) {
        const int n = idx >> 8, k = idx & 255;
        const int kk = (k < 128) ? k : (k + 256);
        W1bT[idx] = f2bf(W1[(size_t)kk * 256 + n]);
    } else {
        const int j = idx - 256 * 256;
        if (j < 128 * 256) {
            const int n = j >> 8, k = j & 255;
            W2bT[j] = f2bf(W2[(size_t)k * 128 + n]);
        }
    }
}

// ---------------------------------------------------------------------------
// Kernel 4: LDS-free per-wave MLP (transposed MFMA dataflow).
// Wave owns 32 nodes. 32x32x16 bf16 MFMA:
//   A-frag: row=l&31, k=(l>>5)*8+j    B-frag: col=l&31, k=(l>>5)*8+j
//   D-frag: col=l&31, row=(r&3)+8*(r>>2)+4*(l>>5)   [m74/m101-verified]
// GEMM1': HT[c][n] = W1T . XT (+P via C-in); H kept as packed bf16 words.
// GEMM2': OT[j][n] = W2T . HT (+b2 via C-in); B-frags built with
//   v_cvt_pk_bf16_f32 (done in epilogue-1) + permlane32_swap (T12).
// No LDS, no barriers; per-lane P row loads (node = l&31).
// ---------------------------------------------------------------------------
__global__ __launch_bounds__(256) void mlp_mfma(
    const unsigned short* __restrict__ xt, const int* __restrict__ batch,
    const float* __restrict__ P,
    const unsigned short* __restrict__ W1bT, const unsigned short* __restrict__ W2bT,
    const float* __restrict__ b2, float* __restrict__ out, int ntiles)
{
    const int wave = threadIdx.x >> 6, lane = threadIdx.x & 63;
    const int tile = blockIdx.x * 4 + wave;
    if (tile >= ntiles) return;

    const int ll = lane & 31, hi = lane >> 5;
    const int node = tile * 32 + ll;

    // ---- X fragments: 16 x bf16x8 = 64 VGPR (read once, reused 8x) ----
    const unsigned short* xp = xt + (size_t)node * 256 + hi * 8;
    bf16x8 xr[16];
    #pragma unroll
    for (int ks = 0; ks < 16; ++ks)
        xr[ks] = *(const bf16x8*)(xp + ks * 16);

    const int g = batch[node];
    const float* Pg = P + (size_t)g * 256 + hi * 4;

    unsigned hw[64];   // HT as packed bf16 pairs (rows c, col = own node)

    // ---- GEMM1' ----
    #pragma unroll
    for (int ct = 0; ct < 8; ++ct) {
        f32x16 acc;
        {
            const float* pp = Pg + ct * 32;
            float4 p0 = *(const float4*)(pp);
            float4 p1 = *(const float4*)(pp + 8);
            float4 p2 = *(const float4*)(pp + 16);
            float4 p3 = *(const float4*)(pp + 24);
            acc[0]=p0.x;  acc[1]=p0.y;  acc[2]=p0.z;  acc[3]=p0.w;
            acc[4]=p1.x;  acc[5]=p1.y;  acc[6]=p1.z;  acc[7]=p1.w;
            acc[8]=p2.x;  acc[9]=p2.y;  acc[10]=p2.z; acc[11]=p2.w;
            acc[12]=p3.x; acc[13]=p3.y; acc[14]=p3.z; acc[15]=p3.w;
        }
        const unsigned short* wp = W1bT + (size_t)(ct * 32 + ll) * 256 + hi * 8;
        #pragma unroll
        for (int ks = 0; ks < 16; ++ks) {
            bf16x8 afr = *(const bf16x8*)(wp + ks * 16);
            acc = __builtin_amdgcn_mfma_f32_32x32x16_bf16(afr, xr[ks], acc, 0, 0, 0);
        }
        // LeakyReLU + pack to bf16 pairs: hw[ct*8+i] = (c_{2i}, c_{2i+1})
        #pragma unroll
        for (int i = 0; i < 8; ++i) {
            float va = acc[2 * i], vb = acc[2 * i + 1];
            va = fmaxf(va, NEG * va);          // LeakyReLU == max(v, 0.01v)
            vb = fmaxf(vb, NEG * vb);
            unsigned w;
            asm("v_cvt_pk_bf16_f32 %0, %1, %2" : "=v"(w) : "v"(va), "v"(vb));
            hw[ct * 8 + i] = w;
        }
    }

    // ---- GEMM2' ----
    #pragma unroll
    for (int jt = 0; jt < 4; ++jt) {
        f32x16 acc;
        {
            const float* bp = b2 + jt * 32 + hi * 4;
            float4 q0 = *(const float4*)(bp);
            float4 q1 = *(const float4*)(bp + 8);
            float4 q2 = *(const float4*)(bp + 16);
            float4 q3 = *(const float4*)(bp + 24);
            acc[0]=q0.x;  acc[1]=q0.y;  acc[2]=q0.z;  acc[3]=q0.w;
            acc[4]=q1.x;  acc[5]=q1.y;  acc[6]=q1.z;  acc[7]=q1.w;
            acc[8]=q2.x;  acc[9]=q2.y;  acc[10]=q2.z; acc[11]=q2.w;
            acc[12]=q3.x; acc[13]=q3.y; acc[14]=q3.z; acc[15]=q3.w;
        }
        const unsigned short* wp = W2bT + (size_t)(jt * 32 + ll) * 256 + hi * 8;
        #pragma unroll
        for (int ks = 0; ks < 16; ++ks) {
            bf16x8 afr = *(const bf16x8*)(wp + ks * 16);
            // B-frag: HT rows c = ks*16 .. ks*16+15 at own node column
            const int b = (ks >> 1) * 8 + (ks & 1) * 4;
            unsigned wA = hw[b], wB = hw[b + 1], wC = hw[b + 2], wD = hw[b + 3];
            PLSWAP(wA, wC);   // wA = b0 (c0c1|c8c9),   wC = b2 (c4c5|c12c13)
            PLSWAP(wB, wD);   // wB = b1 (c2c3|c10c11), wD = b3 (c6c7|c14c15)
            i32x4 fw; fw[0] = (int)wA; fw[1] = (int)wB; fw[2] = (int)wC; fw[3] = (int)wD;
            bf16x8 bfr = __builtin_bit_cast(bf16x8, fw);
            acc = __builtin_amdgcn_mfma_f32_32x32x16_bf16(afr, bfr, acc, 0, 0, 0);
        }
        float* op = out + (size_t)node * 128 + jt * 32 + hi * 4;
        *(float4*)(op)      = make_float4(acc[0],  acc[1],  acc[2],  acc[3]);
        *(float4*)(op + 8)  = make_float4(acc[4],  acc[5],  acc[6],  acc[7]);
        *(float4*)(op + 16) = make_float4(acc[8],  acc[9],  acc[10], acc[11]);
        *(float4*)(op + 24) = make_float4(acc[12], acc[13], acc[14], acc[15]);
    }
}

// ---------------------------------------------------------------------------
extern "C" void kernel_launch(void* const* d_in, const int* in_sizes, int n_in,
                              void* d_out, int out_size, void* d_ws, size_t ws_size,
                              hipStream_t stream)
{
    const float* h_topo = (const float*)d_in[0];
    const float* h_geom = (const float*)d_in[1];
    const int*   batch  = (const int*)  d_in[2];
    const float* W1     = (const float*)d_in[3];
    const float* b1     = (const float*)d_in[4];
    const float* W2     = (const float*)d_in[5];
    const float* b2     = (const float*)d_in[6];
    float* out = (float*)d_out;

    const int N      = in_sizes[0] / D;    // 200000 (32 | N)
    const int ntiles = (N + 31) / 32;      // 6250

    float*          pooled = (float*)d_ws;                          // 512*512 f32
    float*          P      = pooled + (size_t)NUM_GRAPHS * 512;     // 512*256 f32
    unsigned short* W1bT   = (unsigned short*)(P + (size_t)NUM_GRAPHS * 256);
    unsigned short* W2bT   = W1bT + 256 * 256;

    const size_t small_bytes = (size_t)(NUM_GRAPHS * 512 + NUM_GRAPHS * 256) * 4
                             + (size_t)(256 * 256 + 128 * 256) * 2;   // ~1.7 MB
    const size_t xt_bytes = (size_t)N * 256 * 2;                       // 102.4 MB

    // xt: plain node-major bf16 copy of X. Prefer ws; else alias d_out
    // (each wave fully reads its 32-node xt rows before its final stores,
    //  which hit exactly the same byte range; pool regenerates xt every call).
    unsigned short* xt;
    if (ws_size >= small_bytes + xt_bytes)
        xt = (unsigned short*)((char*)d_ws + small_bytes);
    else
        xt = (unsigned short*)d_out;

    wconv_kernel<<<(256 * 256 + 128 * 256) / 256, 256, 0, stream>>>(W1, W2, W1bT, W2bT);
    pool_kernel<<<dim3(NUM_GRAPHS, 2), 256, 0, stream>>>(h_topo, h_geom, batch, N,
                                                         pooled, xt);
    pmat_kernel<<<NUM_GRAPHS, 256, 0, stream>>>(pooled, W1, b1, P);

    mlp_mfma<<<(ntiles + 3) / 4, 256, 0, stream>>>(xt, batch, P, W1bT, W2bT, b2,
                                                   out, ntiles);
}

// Round 6
// 206.333 us; speedup vs baseline: 1.4585x; 1.4585x over previous
//
#include <hip/hip_runtime.h>
#include <math.h>

#define NUM_GRAPHS 512
#define D 128
#define NEG 0.01f
#define BN 64   // nodes per tile / block in MFMA MLP kernel

typedef __attribute__((ext_vector_type(8))) short  bf16x8;  // MFMA A/B frag
typedef __attribute__((ext_vector_type(4))) float  f32x4;   // MFMA C/D frag

__device__ __forceinline__ unsigned short f2bf(float f) {
    unsigned u = __float_as_uint(f);
    u += 0x7fffu + ((u >> 16) & 1u);   // RNE
    return (unsigned short)(u >> 16);
}

__device__ __forceinline__ uint2 pack4(float4 v) {
    uint2 pk;
    pk.x = (unsigned)f2bf(v.x) | ((unsigned)f2bf(v.y) << 16);
    pk.y = (unsigned)f2bf(v.z) | ((unsigned)f2bf(v.w) << 16);
    return pk;
}

// swizzled ushort index within a 64x256 tile: row*256 + (k ^ ((row&7)<<3))
__device__ __forceinline__ int swz(int row, int k) {
    return row * 256 + (k ^ ((row & 7) << 3));
}

#define GLD16(gsrc, ldst)                                                    \
    __builtin_amdgcn_global_load_lds(                                        \
        (const __attribute__((address_space(1))) void*)(gsrc),               \
        (__attribute__((address_space(3))) void*)(ldst), 16, 0, 0)

// raw barrier that does NOT drain vmcnt (keeps global prefetch in flight);
// lgkmcnt(0) publishes LDS writes / retires LDS reads.
#define LDS_BARRIER()                                                        \
    do {                                                                     \
        asm volatile("s_waitcnt lgkmcnt(0)" ::: "memory");                   \
        __builtin_amdgcn_s_barrier();                                        \
        asm volatile("" ::: "memory");                                       \
    } while (0)

// ---------------------------------------------------------------------------
// Kernel 1: per-graph segment max+mean AND bf16 tile-blocked pre-swizzled copy
// of X. grid=(NUM_GRAPHS,2) [y:0=topo,1=geom], block=256. 2-row unrolled.
// ---------------------------------------------------------------------------
__global__ __launch_bounds__(256) void pool_kernel(
    const float* __restrict__ h_topo, const float* __restrict__ h_geom,
    const int* __restrict__ batch, int N, float* __restrict__ pooled,
    unsigned short* __restrict__ xt)
{
    const int g = blockIdx.x, t = blockIdx.y;
    const float* __restrict__ h = t ? h_geom : h_topo;
    const int koff = t ? 128 : 0;

    int lo = 0, hi = N;
    while (lo < hi) { int m = (lo + hi) >> 1; if (batch[m] < g) lo = m + 1; else hi = m; }
    const int start = lo; hi = N;
    while (lo < hi) { int m = (lo + hi) >> 1; if (batch[m] < g + 1) lo = m + 1; else hi = m; }
    const int end = lo;

    const int c = threadIdx.x & 31;   // float4 column
    const int r = threadIdx.x >> 5;   // 0..7 row phase
    const int kk = koff + c * 4;

    float4 mx  = make_float4(-INFINITY, -INFINITY, -INFINITY, -INFINITY);
    float4 mx2 = mx;
    float4 sm  = make_float4(0.f, 0.f, 0.f, 0.f);
    float4 sm2 = sm;

    int row = start + r;
    for (; row + 8 < end; row += 16) {
        float4 v = *(const float4*)(h + (size_t)row * D + c * 4);
        float4 w = *(const float4*)(h + (size_t)(row + 8) * D + c * 4);
        mx.x  = fmaxf(mx.x,  v.x); mx.y  = fmaxf(mx.y,  v.y);
        mx.z  = fmaxf(mx.z,  v.z); mx.w  = fmaxf(mx.w,  v.w);
        sm.x += v.x; sm.y += v.y; sm.z += v.z; sm.w += v.w;
        mx2.x = fmaxf(mx2.x, w.x); mx2.y = fmaxf(mx2.y, w.y);
        mx2.z = fmaxf(mx2.z, w.z); mx2.w = fmaxf(mx2.w, w.w);
        sm2.x += w.x; sm2.y += w.y; sm2.z += w.z; sm2.w += w.w;
        *(uint2*)(xt + (size_t)(row >> 6) * 16384 + swz(row & 63, kk)) = pack4(v);
        *(uint2*)(xt + (size_t)((row + 8) >> 6) * 16384 + swz((row + 8) & 63, kk)) = pack4(w);
    }
    if (row < end) {
        float4 v = *(const float4*)(h + (size_t)row * D + c * 4);
        mx.x  = fmaxf(mx.x,  v.x); mx.y  = fmaxf(mx.y,  v.y);
        mx.z  = fmaxf(mx.z,  v.z); mx.w  = fmaxf(mx.w,  v.w);
        sm.x += v.x; sm.y += v.y; sm.z += v.z; sm.w += v.w;
        *(uint2*)(xt + (size_t)(row >> 6) * 16384 + swz(row & 63, kk)) = pack4(v);
    }
    mx.x = fmaxf(mx.x, mx2.x); mx.y = fmaxf(mx.y, mx2.y);
    mx.z = fmaxf(mx.z, mx2.z); mx.w = fmaxf(mx.w, mx2.w);
    sm.x += sm2.x; sm.y += sm2.y; sm.z += sm2.z; sm.w += sm2.w;

    __shared__ float4 smx[256], ssm[256];
    smx[threadIdx.x] = mx; ssm[threadIdx.x] = sm;
    __syncthreads();
    #pragma unroll
    for (int s = 4; s > 0; s >>= 1) {
        if (r < s) {
            float4 a = smx[threadIdx.x + s * 32];
            float4 b = ssm[threadIdx.x + s * 32];
            float4 m0 = smx[threadIdx.x];
            float4 s0 = ssm[threadIdx.x];
            m0.x = fmaxf(m0.x, a.x); m0.y = fmaxf(m0.y, a.y);
            m0.z = fmaxf(m0.z, a.z); m0.w = fmaxf(m0.w, a.w);
            s0.x += b.x; s0.y += b.y; s0.z += b.z; s0.w += b.w;
            smx[threadIdx.x] = m0; ssm[threadIdx.x] = s0;
        }
        __syncthreads();
    }
    if (r == 0) {
        float4 m0 = smx[threadIdx.x], s0 = ssm[threadIdx.x];
        const float inv = 1.0f / fmaxf((float)(end - start), 1.0f);
        float4 mean = make_float4(s0.x * inv, s0.y * inv, s0.z * inv, s0.w * inv);
        if (end <= start) { m0 = make_float4(0,0,0,0); mean = make_float4(0,0,0,0); }
        float* dst = pooled + (size_t)g * 512 + t * 256;
        *(float4*)(dst + c * 4)       = m0;
        *(float4*)(dst + 128 + c * 4) = mean;
    }
}

// ---------------------------------------------------------------------------
// Kernel 2: per-graph bias P[g][j] = b1[j] + pooled[g] . W1[pooled rows][j]
// ---------------------------------------------------------------------------
__global__ __launch_bounds__(256) void pmat_kernel(
    const float* __restrict__ pooled, const float* __restrict__ W1,
    const float* __restrict__ b1, float* __restrict__ P)
{
    const int g = blockIdx.x;
    const int j = threadIdx.x;

    __shared__ float pl[512];
    pl[j]       = pooled[(size_t)g * 512 + j];
    pl[j + 256] = pooled[(size_t)g * 512 + 256 + j];
    __syncthreads();

    float acc = b1[j];
    #pragma unroll 8
    for (int k = 0; k < 256; ++k)          // t_max,t_mean -> W1 rows 128..383
        acc += pl[k] * W1[(size_t)(128 + k) * 256 + j];
    #pragma unroll 8
    for (int k = 0; k < 256; ++k)          // g_max,g_mean -> W1 rows 512..767
        acc += pl[256 + k] * W1[(size_t)(512 + k) * 256 + j];

    P[(size_t)g * 256 + j] = acc;
}

// ---------------------------------------------------------------------------
// Kernel 3: weight pre-convert to transposed bf16.
// ---------------------------------------------------------------------------
__global__ __launch_bounds__(256) void wconv_kernel(
    const float* __restrict__ W1, const float* __restrict__ W2,
    unsigned short* __restrict__ W1bT, unsigned short* __restrict__ W2bT)
{
    const int idx = blockIdx.x * 256 + threadIdx.x;
    if (idx < 256 * 256) {
        const int n = idx >> 8, k = idx & 255;
        const int kk = (k < 128) ? k : (k + 256);
        W1bT[idx] = f2bf(W1[(size_t)kk * 256 + n]);
    } else {
        const int j = idx - 256 * 256;
        if (j < 128 * 256) {
            const int n = j >> 8, k = j & 255;
            W2bT[j] = f2bf(W2[(size_t)k * 128 + n]);
        }
    }
}

// ---------------------------------------------------------------------------
// Kernel 4: fused MFMA MLP, DMA-staged, 1-deep weight-register pipeline.
//  - stage X tile via global_load_lds(16B); W1 ks=0 frags preloaded alongside
//    (both drain at the first __syncthreads, hiding under each other)
//  - GEMM1: per ks, prefetch ks+1 W-frags into rotating bfr[2][4], MFMA ks
//  - GEMM2 ks=0 W-frags issued BEFORE barrier 2; barriers 2/3 are raw
//    s_barrier + lgkmcnt(0) only, so the vm prefetch stays in flight
// ---------------------------------------------------------------------------
__global__ __launch_bounds__(256, 3) void mlp_mfma(
    const unsigned short* __restrict__ xt, const int* __restrict__ batch,
    const float* __restrict__ P,
    const unsigned short* __restrict__ W1bT, const unsigned short* __restrict__ W2bT,
    const float* __restrict__ b2, float* __restrict__ out, int N)
{
    __shared__ unsigned short xs[64 * 256];   // 32 KB, X then H (swz layout)
    __shared__ int gid[64];

    const int tid  = threadIdx.x;
    const int wave = tid >> 6, lane = tid & 63;
    const int base = blockIdx.x * BN;
    const size_t tbase = (size_t)blockIdx.x * 16384;

    // ---- DMA stage: tile -> LDS, linear copy (2048 x 16B total) ----
    #pragma unroll
    for (int c = 0; c < 8; ++c) {
        const int off = wave * 4096 + c * 512;           // ushort units
        GLD16(xt + tbase + off + lane * 8, xs + off);
    }
    if (tid < 64) gid[tid] = batch[min(base + tid, N - 1)];

    const int g0 = batch[base];
    const int g1 = batch[min(base + 63, N - 1)];
    const bool uni = (g0 == g1);

    const int lhi = lane >> 4;   // 0..3
    const int llo = lane & 15;   // 0..15

    const unsigned short* w1p = W1bT + (size_t)(wave * 64 + llo) * 256 + lhi * 8;
    const unsigned short* w2p = W2bT + (size_t)(wave * 32 + llo) * 256 + lhi * 8;

    float pf[4];
    if (uni) {
        #pragma unroll
        for (int ct = 0; ct < 4; ++ct)
            pf[ct] = P[(size_t)g0 * 256 + wave * 64 + ct * 16 + llo];
    }

    // ---- preload GEMM1 ks=0 weight frags (hides under stage drain) ----
    bf16x8 bfr[2][4];
    #pragma unroll
    for (int ct = 0; ct < 4; ++ct)
        bfr[0][ct] = *(const bf16x8*)(w1p + (size_t)ct * 16 * 256);

    asm volatile("s_waitcnt vmcnt(0)" ::: "memory");
    __syncthreads();

    // ---- GEMM1, 1-deep pipelined over ks ----
    f32x4 acc[4][4];
    #pragma unroll
    for (int rt = 0; rt < 4; ++rt)
        #pragma unroll
        for (int ct = 0; ct < 4; ++ct) {
            const float p = uni ? pf[ct] : 0.f;
            acc[rt][ct] = (f32x4){p, p, p, p};
        }

    #pragma unroll
    for (int ks = 0; ks < 8; ++ks) {
        if (ks < 7) {
            const int kbn = (ks + 1) * 32;
            #pragma unroll
            for (int ct = 0; ct < 4; ++ct)
                bfr[(ks + 1) & 1][ct] = *(const bf16x8*)(w1p + (size_t)ct * 16 * 256 + kbn);
        }
        const int kb = ks * 32 + lhi * 8;
        bf16x8 afr[4];
        #pragma unroll
        for (int rt = 0; rt < 4; ++rt)
            afr[rt] = *(const bf16x8*)&xs[swz(rt * 16 + llo, kb)];
        __builtin_amdgcn_s_setprio(1);
        #pragma unroll
        for (int rt = 0; rt < 4; ++rt)
            #pragma unroll
            for (int ct = 0; ct < 4; ++ct)
                acc[rt][ct] = __builtin_amdgcn_mfma_f32_16x16x32_bf16(
                    afr[rt], bfr[ks & 1][ct], acc[rt][ct], 0, 0, 0);
        __builtin_amdgcn_s_setprio(0);
    }

    // ---- preload GEMM2 ks=0 weight frags (stay in flight across barriers) ----
    bf16x8 bfr2[2][2];
    #pragma unroll
    for (int ct = 0; ct < 2; ++ct)
        bfr2[0][ct] = *(const bf16x8*)(w2p + (size_t)ct * 16 * 256);

    LDS_BARRIER();   // all waves done reading X (lgkm only; vm stays pending)

    // ---- epilogue 1: (+P if boundary tile), LeakyReLU, H -> xs (bf16) ----
    #pragma unroll
    for (int rt = 0; rt < 4; ++rt) {
        #pragma unroll
        for (int ct = 0; ct < 4; ++ct) {
            const int col = wave * 64 + ct * 16 + llo;
            #pragma unroll
            for (int q = 0; q < 4; ++q) {
                const int row = rt * 16 + lhi * 4 + q;
                float v = acc[rt][ct][q];
                if (!uni) v += P[(size_t)gid[row] * 256 + col];
                v = fmaxf(v, NEG * v);   // LeakyReLU
                xs[swz(row, col)] = f2bf(v);
            }
        }
    }

    LDS_BARRIER();   // H published

    // ---- GEMM2, 1-deep pipelined over ks ----
    f32x4 acc2[4][2];
    #pragma unroll
    for (int ct = 0; ct < 2; ++ct) {
        const float bv = b2[wave * 32 + ct * 16 + llo];
        #pragma unroll
        for (int rt = 0; rt < 4; ++rt)
            acc2[rt][ct] = (f32x4){bv, bv, bv, bv};
    }
    #pragma unroll
    for (int ks = 0; ks < 8; ++ks) {
        if (ks < 7) {
            const int kbn = (ks + 1) * 32;
            #pragma unroll
            for (int ct = 0; ct < 2; ++ct)
                bfr2[(ks + 1) & 1][ct] = *(const bf16x8*)(w2p + (size_t)ct * 16 * 256 + kbn);
        }
        const int kb = ks * 32 + lhi * 8;
        bf16x8 afr[4];
        #pragma unroll
        for (int rt = 0; rt < 4; ++rt)
            afr[rt] = *(const bf16x8*)&xs[swz(rt * 16 + llo, kb)];
        __builtin_amdgcn_s_setprio(1);
        #pragma unroll
        for (int rt = 0; rt < 4; ++rt)
            #pragma unroll
            for (int ct = 0; ct < 2; ++ct)
                acc2[rt][ct] = __builtin_amdgcn_mfma_f32_16x16x32_bf16(
                    afr[rt], bfr2[ks & 1][ct], acc2[rt][ct], 0, 0, 0);
        __builtin_amdgcn_s_setprio(0);
    }

    // ---- store out (f32) ----
    #pragma unroll
    for (int rt = 0; rt < 4; ++rt)
        #pragma unroll
        for (int ct = 0; ct < 2; ++ct)
            #pragma unroll
            for (int q = 0; q < 4; ++q) {
                const int row  = rt * 16 + lhi * 4 + q;
                const int node = base + row;
                if (node < N)
                    out[(size_t)node * 128 + wave * 32 + ct * 16 + llo] = acc2[rt][ct][q];
            }
}

// ---------------------------------------------------------------------------
extern "C" void kernel_launch(void* const* d_in, const int* in_sizes, int n_in,
                              void* d_out, int out_size, void* d_ws, size_t ws_size,
                              hipStream_t stream)
{
    const float* h_topo = (const float*)d_in[0];
    const float* h_geom = (const float*)d_in[1];
    const int*   batch  = (const int*)  d_in[2];
    const float* W1     = (const float*)d_in[3];
    const float* b1     = (const float*)d_in[4];
    const float* W2     = (const float*)d_in[5];
    const float* b2     = (const float*)d_in[6];
    float* out = (float*)d_out;

    const int N = in_sizes[0] / D;   // 200000

    float*          pooled = (float*)d_ws;                          // 512*512 f32
    float*          P      = pooled + (size_t)NUM_GRAPHS * 512;     // 512*256 f32
    unsigned short* W1bT   = (unsigned short*)(P + (size_t)NUM_GRAPHS * 256);
    unsigned short* W2bT   = W1bT + 256 * 256;

    const size_t small_bytes = (size_t)(NUM_GRAPHS * 512 + NUM_GRAPHS * 256) * 4
                             + (size_t)(256 * 256 + 128 * 256) * 2;   // ~1.7 MB
    const size_t xt_bytes = (size_t)N * 256 * 2;                       // 102.4 MB

    // xt: pre-swizzled bf16 tile copy of X. Prefer ws; else alias d_out
    // (tile t's xt bytes == tile t's out bytes; the owning block fully reads
    //  xt[t] before storing out[t], and pool regenerates xt every call).
    unsigned short* xt;
    if (ws_size >= small_bytes + xt_bytes)
        xt = (unsigned short*)((char*)d_ws + small_bytes);
    else
        xt = (unsigned short*)d_out;

    wconv_kernel<<<(256 * 256 + 128 * 256) / 256, 256, 0, stream>>>(W1, W2, W1bT, W2bT);
    pool_kernel<<<dim3(NUM_GRAPHS, 2), 256, 0, stream>>>(h_topo, h_geom, batch, N,
                                                         pooled, xt);
    pmat_kernel<<<NUM_GRAPHS, 256, 0, stream>>>(pooled, W1, b1, P);

    mlp_mfma<<<N / BN, 256, 0, stream>>>(xt, batch, P, W1bT, W2bT, b2, out, N);
}